// Round 4
// baseline (1004.762 us; speedup 1.0000x reference)
//
#include <hip/hip_runtime.h>
#include <stdint.h>

// out = x @ dequant(W)^T + bias
// x: [M,K] fp32 (M=B*S=8192), W_q: [N,K] int32 codes in [0,4),
// scale/zp: [N,K/G] fp32 (G=64), bias: [N] fp32, out: [M,N] fp32.
//
// R4: barrier-free wave-private GEMM with EXPLICIT waitcnt discipline
// (R3 NaN'd because the compiler cannot see the global_load_lds -> ds_read
// hazard; the barrier used to provide that wait). Per iter:
//   lgkmcnt(0) guard -> stage 8 loads into nxt -> vmcnt(8) -> ds_read cur
//   -> 16 MFMA.  vmcnt never drains to 0 inside the loop (hipBLASLt style).

typedef __attribute__((ext_vector_type(4))) float  f32x4;
typedef __attribute__((ext_vector_type(4))) int    i32x4;
typedef __attribute__((ext_vector_type(8))) __bf16 bf16x8;
typedef __attribute__((ext_vector_type(4))) unsigned short u16x4;

__device__ __forceinline__ unsigned short f2bf(float f) {
  unsigned u = __builtin_bit_cast(unsigned, f);
  u += 0x7fffu + ((u >> 16) & 1u);   // round-to-nearest-even
  return (unsigned short)(u >> 16);
}

__device__ __forceinline__ void async16(const void* g, void* l) {
  __builtin_amdgcn_global_load_lds(
      (const __attribute__((address_space(1))) unsigned int*)g,
      (__attribute__((address_space(3))) unsigned int*)l, 16, 0, 0);
}

// ---------------- fused prepass: x->bf16 and dequant W->bf16 ----------------
__global__ __launch_bounds__(256) void prep_kernel(
    const float* __restrict__ x, unsigned short* __restrict__ xb, int xchunks,
    const int* __restrict__ wq, const float* __restrict__ scale,
    const float* __restrict__ zp, unsigned short* __restrict__ wb,
    int wchunks, int K, int G) {
  int xblocks = (xchunks + 255) >> 8;
  if ((int)blockIdx.x < xblocks) {
    int i = blockIdx.x * 256 + threadIdx.x;
    if (i >= xchunks) return;
    f32x4 a = ((const f32x4*)x)[i];
    u16x4 o;
    o[0] = f2bf(a[0]); o[1] = f2bf(a[1]); o[2] = f2bf(a[2]); o[3] = f2bf(a[3]);
    *(u16x4*)(xb + (size_t)i * 4) = o;
  } else {
    int i = (blockIdx.x - xblocks) * 256 + threadIdx.x;
    if (i >= wchunks) return;
    int k4 = i * 4;
    int n = k4 / K, kk = k4 % K;
    int ng = K / G;
    int g = kk / G;
    float s = scale[(size_t)n * ng + g];
    float b = -zp[(size_t)n * ng + g] * s;   // w = q*s + b
    i32x4 qv = ((const i32x4*)wq)[i];
    u16x4 o;
    o[0] = f2bf((float)qv[0] * s + b); o[1] = f2bf((float)qv[1] * s + b);
    o[2] = f2bf((float)qv[2] * s + b); o[3] = f2bf((float)qv[3] * s + b);
    *(u16x4*)(wb + (size_t)i * 4) = o;
  }
}

// ---------------- main GEMM: C[M,N] = A[M,K] * B[N,K]^T + bias ----------------
// 1 wave per block, 64x64 tile, BK=32, private double-buffered LDS, no barrier.
__global__ __launch_bounds__(64) void gemm_bt_kernel(
    const unsigned short* __restrict__ A,   // M x K bf16
    const unsigned short* __restrict__ B,   // N x K bf16
    const float* __restrict__ bias,
    float* __restrict__ C, int M, int N, int K) {
  __shared__ __align__(16) unsigned short lds[8192];  // 16 KB: 2 x (A 2048 | B 2048)

  const int l = threadIdx.x;                // 0..63
  const int q = l >> 4, r = l & 15;         // MFMA K-slice / row-in-16
  const int m0 = blockIdx.y * 64;
  const int n0 = blockIdx.x * 64;

  // Staging: call j covers rows 16j..16j+15. Lane l -> row (l>>2)+16j,
  // LDS slot l&3; slot s of a row holds GLOBAL chunk s ^ ((row>>1)&3)
  // = s ^ ((l>>3)&3)  (XOR swizzle; measured conflict-free in R2).
  const int srow = l >> 2;
  const int gchunk = (l & 3) ^ ((l >> 3) & 3);
  const unsigned short* aG = A + (size_t)(m0 + srow) * K + gchunk * 8;
  const unsigned short* bG = B + (size_t)(n0 + srow) * K + gchunk * 8;
  const size_t rstep = (size_t)16 * K;      // +16 rows

  unsigned short* cur = lds;
  unsigned short* nxt = lds + 4096;

  // Read-side: chunk q of row (i*16+r) lives in slot q ^ ((r>>1)&3).
  const int qc = (q ^ ((r >> 1) & 3)) * 8;

  // preamble: stage K-step 0 into cur (8 loads outstanding)
#pragma unroll
  for (int j = 0; j < 4; ++j) {
    async16(aG + (size_t)j * rstep, cur + j * 512 + l * 8);
    async16(bG + (size_t)j * rstep, cur + 2048 + j * 512 + l * 8);
  }

  f32x4 acc[4][4] = {};

#pragma unroll 1
  for (int kk = 0; kk < K; kk += 32) {
    // WAR guard: ds_reads of the buffer we're about to overwrite (read last
    // iter as cur) must be retired before the DMA can land in it.
    asm volatile("s_waitcnt lgkmcnt(0)" ::: "memory");

    // stage next K-step into nxt (wrap at K so vmcnt count stays invariant)
    int kn = kk + 32; if (kn == K) kn = 0;
    const unsigned short* aGk = aG + kn;
    const unsigned short* bGk = bG + kn;
#pragma unroll
    for (int j = 0; j < 4; ++j) {
      async16(aGk + (size_t)j * rstep, nxt + j * 512 + l * 8);
      async16(bGk + (size_t)j * rstep, nxt + 2048 + j * 512 + l * 8);
    }

    // wait until only the 8 just-issued remain: cur's 8 have landed
    asm volatile("s_waitcnt vmcnt(8)" ::: "memory");

    bf16x8 af[4], bf[4];
#pragma unroll
    for (int i = 0; i < 4; ++i) {
      af[i] = *(const bf16x8*)&cur[(i * 16 + r) * 32 + qc];
      bf[i] = *(const bf16x8*)&cur[2048 + (i * 16 + r) * 32 + qc];
    }
#pragma unroll
    for (int i = 0; i < 4; ++i)
#pragma unroll
      for (int j = 0; j < 4; ++j)
        acc[i][j] = __builtin_amdgcn_mfma_f32_16x16x32_bf16(af[i], bf[j], acc[i][j], 0, 0, 0);

    unsigned short* t = cur; cur = nxt; nxt = t;   // runtime swap
  }

  // drain stray wrap-prefetch before touching anything else / ending
  asm volatile("s_waitcnt vmcnt(0)" ::: "memory");

  // epilogue: C/D layout col = lane&15, row = quad*4 + reg
  float bv[4];
#pragma unroll
  for (int j = 0; j < 4; ++j) bv[j] = bias[n0 + j * 16 + r];
#pragma unroll
  for (int i = 0; i < 4; ++i) {
    int mbase = m0 + i * 16 + q * 4;
#pragma unroll
    for (int e = 0; e < 4; ++e) {
      float* crow = C + (size_t)(mbase + e) * N + n0 + r;
#pragma unroll
      for (int j = 0; j < 4; ++j)
        crow[j * 16] = acc[i][j][e] + bv[j];
    }
  }
}

// ---------------- correctness fallback (only if ws too small) ----------------
__global__ __launch_bounds__(256) void naive_kernel(
    const float* __restrict__ x, const int* __restrict__ wq,
    const float* __restrict__ scale, const float* __restrict__ zp,
    const float* __restrict__ bias, float* __restrict__ out,
    int M, int N, int K, int G) {
  int idx = blockIdx.x * 256 + threadIdx.x;
  if (idx >= M * N) return;
  int m = idx / N, n = idx % N;
  const float* xr = x + (size_t)m * K;
  const int* wr = wq + (size_t)n * K;
  int ng = K / G;
  float acc = 0.f;
  for (int g = 0; g < ng; ++g) {
    float s = scale[(size_t)n * ng + g];
    float b = -zp[(size_t)n * ng + g] * s;
    for (int k = 0; k < G; ++k)
      acc += xr[g * G + k] * ((float)wr[g * G + k] * s + b);
  }
  out[idx] = acc + bias[n];
}

extern "C" void kernel_launch(void* const* d_in, const int* in_sizes, int n_in,
                              void* d_out, int out_size, void* d_ws, size_t ws_size,
                              hipStream_t stream) {
  const float* x     = (const float*)d_in[0];
  const int*   wq    = (const int*)d_in[1];
  const float* scale = (const float*)d_in[2];
  const float* zp    = (const float*)d_in[3];
  const float* bias  = (const float*)d_in[4];
  float* out = (float*)d_out;

  const int N  = in_sizes[4];
  const int K  = in_sizes[1] / N;
  const int ng = in_sizes[2] / N;
  const int G  = K / ng;
  const int M  = in_sizes[0] / K;

  size_t xb_bytes = (size_t)M * K * 2;
  size_t wb_bytes = (size_t)N * K * 2;
  if (ws_size < xb_bytes + wb_bytes) {
    int total = M * N;
    naive_kernel<<<dim3((total + 255) / 256), dim3(256), 0, stream>>>(
        x, wq, scale, zp, bias, out, M, N, K, G);
    return;
  }

  unsigned short* xb = (unsigned short*)d_ws;
  unsigned short* wb = (unsigned short*)((char*)d_ws + xb_bytes);

  int xchunks = M * K / 4;
  int wchunks = N * K / 4;
  int xblocks = (xchunks + 255) / 256;
  int wblocks = (wchunks + 255) / 256;
  prep_kernel<<<dim3(xblocks + wblocks), dim3(256), 0, stream>>>(
      x, xb, xchunks, wq, scale, zp, wb, wchunks, K, G);

  dim3 grid(N / 64, M / 64);
  gemm_bt_kernel<<<grid, dim3(64), 0, stream>>>(xb, wb, bias, out, M, N, K);
}

// Round 5
// 579.001 us; speedup vs baseline: 1.7353x; 1.7353x over previous
//
#include <hip/hip_runtime.h>
#include <stdint.h>

// out = x @ dequant(W)^T + bias
// x: [M,K] fp32 (M=B*S=8192), W_q: [N,K] int32 codes in [0,4),
// scale/zp: [N,K/G] fp32 (G=64), bias: [N] fp32, out: [M,N] fp32.
//
// R5: shared 128x128 tile (R2's reuse: FETCH ~0.4GB) + pipelined K-loop with
// RAW s_barrier (asm, invisible to SIInsertWaitcnts) so vmcnt NEVER drains
// to 0 inside the loop (R4 proved the compiler doesn't track the
// global_load_lds->ds_read hazard; we place all waits by hand):
//   issue stage->nxt | vmcnt(4) | s_barrier | ds_read cur + lgkmcnt(0)
//   | s_barrier | 16 MFMA | swap.

typedef __attribute__((ext_vector_type(4))) float  f32x4;
typedef __attribute__((ext_vector_type(4))) int    i32x4;
typedef __attribute__((ext_vector_type(8))) __bf16 bf16x8;
typedef __attribute__((ext_vector_type(4))) unsigned short u16x4;

__device__ __forceinline__ unsigned short f2bf(float f) {
  unsigned u = __builtin_bit_cast(unsigned, f);
  u += 0x7fffu + ((u >> 16) & 1u);   // round-to-nearest-even
  return (unsigned short)(u >> 16);
}

__device__ __forceinline__ void async16(const void* g, void* l) {
  __builtin_amdgcn_global_load_lds(
      (const __attribute__((address_space(1))) unsigned int*)g,
      (__attribute__((address_space(3))) unsigned int*)l, 16, 0, 0);
}

// ---------------- fused prepass: x->bf16 and dequant W->bf16 ----------------
__global__ __launch_bounds__(256) void prep_kernel(
    const float* __restrict__ x, unsigned short* __restrict__ xb, int xchunks,
    const int* __restrict__ wq, const float* __restrict__ scale,
    const float* __restrict__ zp, unsigned short* __restrict__ wb,
    int wchunks, int K, int G) {
  int xblocks = (xchunks + 255) >> 8;
  if ((int)blockIdx.x < xblocks) {
    int i = blockIdx.x * 256 + threadIdx.x;
    if (i >= xchunks) return;
    f32x4 a = ((const f32x4*)x)[i];
    u16x4 o;
    o[0] = f2bf(a[0]); o[1] = f2bf(a[1]); o[2] = f2bf(a[2]); o[3] = f2bf(a[3]);
    *(u16x4*)(xb + (size_t)i * 4) = o;
  } else {
    int i = (blockIdx.x - xblocks) * 256 + threadIdx.x;
    if (i >= wchunks) return;
    int k4 = i * 4;
    int n = k4 / K, kk = k4 % K;
    int ng = K / G;
    int g = kk / G;
    float s = scale[(size_t)n * ng + g];
    float b = -zp[(size_t)n * ng + g] * s;   // w = q*s + b
    i32x4 qv = ((const i32x4*)wq)[i];
    u16x4 o;
    o[0] = f2bf((float)qv[0] * s + b); o[1] = f2bf((float)qv[1] * s + b);
    o[2] = f2bf((float)qv[2] * s + b); o[3] = f2bf((float)qv[3] * s + b);
    *(u16x4*)(wb + (size_t)i * 4) = o;
  }
}

// ---------------- main GEMM: C[M,N] = A[M,K] * B[N,K]^T + bias ----------------
// 256 threads (4 waves, 2x2), 128x128 tile, BK=32, double-buffered 32KB LDS.
__global__ __launch_bounds__(256, 2) void gemm_bt_kernel(
    const unsigned short* __restrict__ A,   // M x K bf16
    const unsigned short* __restrict__ B,   // N x K bf16
    const float* __restrict__ bias,
    float* __restrict__ C, int M, int N, int K) {
  // buf layout: [A 4096 shorts | B 4096 shorts] x 2
  __shared__ __align__(16) unsigned short lds[16384];  // 32 KB

  const int tid  = threadIdx.x;
  const int lane = tid & 63;
  const int wave = tid >> 6;                // 2x2 waves over 128x128
  const int wm = wave >> 1, wn = wave & 1;
  const int q = lane >> 4, r = lane & 15;   // MFMA K-slice / row-in-16
  const int m0 = blockIdx.y * 128;
  const int n0 = blockIdx.x * 128;

  // Staging (R2 scheme, measured conflict-free): thread tid owns LDS slot
  // (row=tid>>2, slot=tid&3); slot s of row holds GLOBAL chunk
  // s ^ ((row>>1)&3), so this thread fetches that chunk.
  const int srow = tid >> 2, schunk = tid & 3;
  const int gchunk = schunk ^ ((srow >> 1) & 3);
  const unsigned short* aG0 = A + (size_t)(m0 + srow) * K      + gchunk * 8;
  const unsigned short* aG1 = A + (size_t)(m0 + 64 + srow) * K + gchunk * 8;
  const unsigned short* bG0 = B + (size_t)(n0 + srow) * K      + gchunk * 8;
  const unsigned short* bG1 = B + (size_t)(n0 + 64 + srow) * K + gchunk * 8;

  unsigned short* cur = lds;
  unsigned short* nxt = lds + 8192;

  // Read-side: chunk q of row (base16 + r) lives in slot q ^ ((r>>1)&3).
  const int qc = (q ^ ((r >> 1) & 3)) * 8;

  // preamble: stage K-step 0 into cur (4 loads outstanding per thread)
  async16(aG0, cur + tid * 8);
  async16(aG1, cur + 2048 + tid * 8);
  async16(bG0, cur + 4096 + tid * 8);
  async16(bG1, cur + 6144 + tid * 8);

  f32x4 acc[4][4] = {};

#pragma unroll 1
  for (int kk = 0; kk < K; kk += 32) {
    // 1) stage next K-step into nxt (wrap keeps vmcnt count invariant).
    //    WAR on nxt is safe: all waves retired their ds_reads of nxt
    //    (lgkmcnt(0)) before the 2nd barrier of the previous iteration.
    int kn = kk + 32; if (kn == K) kn = 0;
    async16(aG0 + kn, nxt + tid * 8);
    async16(aG1 + kn, nxt + 2048 + tid * 8);
    async16(bG0 + kn, nxt + 4096 + tid * 8);
    async16(bG1 + kn, nxt + 6144 + tid * 8);

    // 2) my 4 loads for cur (issued last iter) landed; new 4 stay in flight
    asm volatile("s_waitcnt vmcnt(4)" ::: "memory");
    // 3) all waves' cur portions landed
    asm volatile("s_barrier" ::: "memory");

    // 4) LDS -> VGPR fragments, then prove retirement
    bf16x8 af[4], bf[4];
#pragma unroll
    for (int i = 0; i < 4; ++i) {
      af[i] = *(const bf16x8*)&cur[(wm * 64 + i * 16 + r) * 32 + qc];
      bf[i] = *(const bf16x8*)&cur[4096 + (wn * 64 + i * 16 + r) * 32 + qc];
    }
    asm volatile("s_waitcnt lgkmcnt(0)" ::: "memory");
    // 5) all waves done reading cur -> next iter may DMA over it
    asm volatile("s_barrier" ::: "memory");

    // 6) compute overlaps the in-flight stage
#pragma unroll
    for (int i = 0; i < 4; ++i)
#pragma unroll
      for (int j = 0; j < 4; ++j)
        acc[i][j] = __builtin_amdgcn_mfma_f32_16x16x32_bf16(af[i], bf[j], acc[i][j], 0, 0, 0);

    unsigned short* t = cur; cur = nxt; nxt = t;   // runtime swap
  }

  // stray wrap-prefetch must land before workgroup LDS dealloc
  asm volatile("s_waitcnt vmcnt(0)" ::: "memory");

  // epilogue: C/D layout col = lane&15, row = quad*4 + reg
  float bv[4];
#pragma unroll
  for (int j = 0; j < 4; ++j) bv[j] = bias[n0 + wn * 64 + j * 16 + r];
#pragma unroll
  for (int i = 0; i < 4; ++i) {
    int mbase = m0 + wm * 64 + i * 16 + q * 4;
#pragma unroll
    for (int e = 0; e < 4; ++e) {
      float* crow = C + (size_t)(mbase + e) * N + n0 + wn * 64 + r;
#pragma unroll
      for (int j = 0; j < 4; ++j)
        crow[j * 16] = acc[i][j][e] + bv[j];
    }
  }
}

// ---------------- correctness fallback (only if ws too small) ----------------
__global__ __launch_bounds__(256) void naive_kernel(
    const float* __restrict__ x, const int* __restrict__ wq,
    const float* __restrict__ scale, const float* __restrict__ zp,
    const float* __restrict__ bias, float* __restrict__ out,
    int M, int N, int K, int G) {
  int idx = blockIdx.x * 256 + threadIdx.x;
  if (idx >= M * N) return;
  int m = idx / N, n = idx % N;
  const float* xr = x + (size_t)m * K;
  const int* wr = wq + (size_t)n * K;
  int ng = K / G;
  float acc = 0.f;
  for (int g = 0; g < ng; ++g) {
    float s = scale[(size_t)n * ng + g];
    float b = -zp[(size_t)n * ng + g] * s;
    for (int k = 0; k < G; ++k)
      acc += xr[g * G + k] * ((float)wr[g * G + k] * s + b);
  }
  out[idx] = acc + bias[n];
}

extern "C" void kernel_launch(void* const* d_in, const int* in_sizes, int n_in,
                              void* d_out, int out_size, void* d_ws, size_t ws_size,
                              hipStream_t stream) {
  const float* x     = (const float*)d_in[0];
  const int*   wq    = (const int*)d_in[1];
  const float* scale = (const float*)d_in[2];
  const float* zp    = (const float*)d_in[3];
  const float* bias  = (const float*)d_in[4];
  float* out = (float*)d_out;

  const int N  = in_sizes[4];
  const int K  = in_sizes[1] / N;
  const int ng = in_sizes[2] / N;
  const int G  = K / ng;
  const int M  = in_sizes[0] / K;

  size_t xb_bytes = (size_t)M * K * 2;
  size_t wb_bytes = (size_t)N * K * 2;
  if (ws_size < xb_bytes + wb_bytes) {
    int total = M * N;
    naive_kernel<<<dim3((total + 255) / 256), dim3(256), 0, stream>>>(
        x, wq, scale, zp, bias, out, M, N, K, G);
    return;
  }

  unsigned short* xb = (unsigned short*)d_ws;
  unsigned short* wb = (unsigned short*)((char*)d_ws + xb_bytes);

  int xchunks = M * K / 4;
  int wchunks = N * K / 4;
  int xblocks = (xchunks + 255) / 256;
  int wblocks = (wchunks + 255) / 256;
  prep_kernel<<<dim3(xblocks + wblocks), dim3(256), 0, stream>>>(
      x, xb, xchunks, wq, scale, zp, wb, wchunks, K, G);

  dim3 grid(N / 128, M / 128);
  gemm_bt_kernel<<<grid, dim3(256), 0, stream>>>(xb, wb, bias, out, M, N, K);
}